// Round 3
// baseline (169.505 us; speedup 1.0000x reference)
//
#include <hip/hip_runtime.h>
#include <hip/hip_bf16.h>

// B=64, S=512, E=256, D=512
#define EDIM 256
#define SDIM 512
#define BDIM 64
#define DDIM 512
#define SPAD 514   // padded S rows per batch in Xp (2 zero rows at front)

// ws byte offsets
#define OFF_XP    0u           // bf16 [64][514][256]  = 16,842,752 B
#define OFF_BFI   16842752u    // bf16 frag-major interior weights = 1,572,864 B
                               //   addr = (((c*2+h)*48 + kt)*4 + t)*1024 + l*16 + j*2
                               //   holds G_int[d = c*128+h*64+t*16+(l&15)][k = kt*32+(l>>4)*8+j]
#define OFF_BFT   18415616u    // bf16 frag-major tail (W1) weights = 262,144 B (same scheme, 8 kt)
#define OFF_CORR  18677760u    // f32  [512][128]  (layout [d][b*2+s])
#define OFF_BI    18939904u    // f32  [512]

// prep grid partition
#define CVT_BLOCKS  4112       // 64*514*32 / 256
#define BF_BASE     4112       // + 448 frag blocks (384 interior + 64 tail)
#define CORR_BASE   4560       // + 4096 corr blocks (512 d x 8 b-chunks)
#define PREP_BLOCKS 8656

typedef __attribute__((ext_vector_type(8))) __bf16 bf16x8;
typedef __attribute__((ext_vector_type(4))) float  f32x4;
typedef __attribute__((ext_vector_type(8))) unsigned short ushort8v;

__device__ __forceinline__ unsigned short f2bf(float f) {
    unsigned int u = __float_as_uint(f);
    u = (u + 0x7fffu + ((u >> 16) & 1u)) >> 16;   // RNE
    return (unsigned short)u;
}

// ============ launch 1: cvt_pad + weight-fragment + edge-correction ============
__global__ __launch_bounds__(256) void prep_all(
    const float* __restrict__ X,
    const float* __restrict__ W1, const float* __restrict__ b1,
    const float* __restrict__ W2, const float* __restrict__ b2,
    const float* __restrict__ W3, const float* __restrict__ b3,
    const float* __restrict__ W4, const float* __restrict__ b4,
    char* __restrict__ wsb)
{
    const int tid = threadIdx.x;

    if (blockIdx.x < CVT_BLOCKS) {
        // ---- bf16 copy of X with 2 zero rows prepended per batch, 8 elem/thread ----
        unsigned short* Xp = (unsigned short*)(wsb + OFF_XP);
        const int i   = blockIdx.x * 256 + tid;    // [0, 64*514*32)
        const int row = i >> 5;                    // b*514 + j
        const int q   = i & 31;                    // 8-elem group
        const int b   = row / SPAD;
        const int j   = row - b * SPAD;
        ushort8v v;
        if (j < 2) {
            v = (ushort8v)0;
        } else {
            const float* src = X + ((size_t)(b * SDIM + j - 2)) * EDIM + q * 8;
            const float4 f0 = *(const float4*)(src);
            const float4 f1 = *(const float4*)(src + 4);
            v[0] = f2bf(f0.x); v[1] = f2bf(f0.y); v[2] = f2bf(f0.z); v[3] = f2bf(f0.w);
            v[4] = f2bf(f1.x); v[5] = f2bf(f1.y); v[6] = f2bf(f1.z); v[7] = f2bf(f1.w);
        }
        *(ushort8v*)(Xp + (size_t)row * EDIM + q * 8) = v;
        return;
    }

    if (blockIdx.x < CORR_BASE) {
        // ---- combined weights in FRAGMENT-MAJOR layout (direct MFMA B-operand) ----
        // G_int[d][k], k = shift*256 + e, shift 0..5 (delta grouping, R0 derivation):
        //   s0: w40 | s1: w30+w40+w41 | s2: w1+w20+w30+w31+w40+w41+w42
        //   s3: w21+w31+w32+w41+w42+w43 | s4: w32+w42+w43 | s5: w43
        const int p  = blockIdx.x - BF_BASE;   // 0..447
        const int t  = tid >> 6;
        const int l  = tid & 63;
        const int fm = l & 15;
        const int hi = l >> 4;
        if (p < 384) {
            const int kt = p % 48;             // shift = kt>>3 is block-uniform
            const int h  = (p / 48) & 1;
            const int c  = p / 96;
            const int d  = c * 128 + h * 64 + t * 16 + fm;
            const int shift = kt >> 3;
            const int e0 = (kt & 7) * 32 + hi * 8;
            ushort8v v;
#pragma unroll
            for (int j = 0; j < 8; ++j) {
                const int e  = e0 + j;
                const int de = d * 256 + e;
                float g;
                if      (shift == 0) g = W4[de*4+0];
                else if (shift == 1) g = W3[de*3+0] + W4[de*4+0] + W4[de*4+1];
                else if (shift == 2) g = W1[de] + W2[de*2+0] + W3[de*3+0] + W3[de*3+1]
                                       + W4[de*4+0] + W4[de*4+1] + W4[de*4+2];
                else if (shift == 3) g = W2[de*2+1] + W3[de*3+1] + W3[de*3+2]
                                       + W4[de*4+1] + W4[de*4+2] + W4[de*4+3];
                else if (shift == 4) g = W3[de*3+2] + W4[de*4+2] + W4[de*4+3];
                else                 g = W4[de*4+3];
                v[j] = f2bf(g);
            }
            *(ushort8v*)(wsb + OFF_BFI + (size_t)((((c*2+h)*48 + kt)*4 + t)*1024 + l*16)) = v;
            if (kt == 0 && hi == 0)   // one lane per d
                ((float*)(wsb + OFF_BI))[d] = b1[d] + b2[d] + 2.0f*b3[d] + 3.0f*b4[d];
        } else {
            const int q  = p - 384;
            const int kt = q % 8;
            const int h  = (q / 8) & 1;
            const int c  = q / 16;
            const int d  = c * 128 + h * 64 + t * 16 + fm;
            const int k0 = kt * 32 + hi * 8;
            ushort8v v;
#pragma unroll
            for (int j = 0; j < 8; ++j) v[j] = f2bf(W1[d * 256 + k0 + j]);
            *(ushort8v*)(wsb + OFF_BFT + (size_t)((((c*2+h)*8 + kt)*4 + t)*1024 + l*16)) = v;
        }
        return;
    }

    // ---- edge correction, block = (d, 8-batch chunk); coalesced weight rows.
    {
        __shared__ float cls[16];
        const int cb = blockIdx.x - CORR_BASE;   // 0..4095
        const int d  = cb >> 3;                  // 0..511
        const int bq = (cb & 7) * 8;             // batch chunk base
        const int e  = tid;                      // 0..255

        if (tid < 16) cls[tid] = 0.f;

        const float w31 = W3[(size_t)d * 768 + 3 * e + 1];
        const float w32 = W3[(size_t)d * 768 + 3 * e + 2];
        const float4 w4v = *(const float4*)(W4 + (size_t)d * 1024 + 4 * e);
        const float w41 = w4v.y, w42 = w4v.z, w43 = w4v.w;

        const float c00 = w31 + w41 + w42;
        const float c01 = w32 + w42 + w43;
        const float c02 = w43;
        __syncthreads();

#pragma unroll
        for (int bi = 0; bi < 8; ++bi) {
            const float* xr = X + (size_t)(bq + bi) * (SDIM * EDIM) + e;
            const float x0 = xr[0], x1 = xr[EDIM], x2 = xr[2 * EDIM];
            float a0 = c00 * x0 + c01 * x1 + c02 * x2;
            float a1 = w41 * x0 + w42 * x1 + w43 * x2;
#pragma unroll
            for (int off = 32; off >= 1; off >>= 1) {
                a0 += __shfl_xor(a0, off, 64);
                a1 += __shfl_xor(a1, off, 64);
            }
            if ((tid & 63) == 0) {
                atomicAdd(&cls[bi * 2 + 0], a0);
                atomicAdd(&cls[bi * 2 + 1], a1);
            }
        }
        __syncthreads();

        if (tid < 16) {
            const int s = tid & 1;
            const float bc = s ? b4[d] : (b3[d] + 2.f * b4[d]);
            ((float*)(wsb + OFF_CORR))[(size_t)d * 128 + bq * 2 + tid] = -cls[tid] - bc;
        }
    }
}

// ============ launch 2: paired GEMM, A-only LDS, B in registers ============
// 512 blocks, each: interior 128x128 tile (K=1536, 48 steps, +corr rows) THEN
// the same strip's tail tile (K=256, 8 steps). Uniform duration, 2 blocks/CU
// co-resident throughout. B loaded global->reg from fragment-major panels
// (L2-resident, one col-block per XCD via chunked swizzle), double-buffered
// 1 k-step ahead. LDS holds only A (2x8KB dbuf) -> per-step LDS traffic
// halves vs R2 (48KB -> 24KB). Counted vmcnt(6) = 2 gll + 4 B-loads in
// flight across barriers; never drained to 0 in-loop.
#define GLL(src, dst) \
    __builtin_amdgcn_global_load_lds((const __attribute__((address_space(1))) void*)(src), \
                                     (__attribute__((address_space(3))) void*)(dst), 16, 0, 0)

__global__ __launch_bounds__(256) void mega(
    const unsigned short* __restrict__ Xp,
    const char* __restrict__ wsb,
    const float* __restrict__ b1,
    float* __restrict__ out)
{
    __shared__ __align__(16) char smem[16384];   // 2 x 8KB A buffers
    const int id0 = blockIdx.x;
    const int id  = (id0 & 7) * 64 + (id0 >> 3);   // XCD-chunked swizzle (512%8==0, bijective)
    const int strip = id & 127;                    // 128 strips x 128 rows
    const int c     = id >> 7;                     // col block 0..3
    const int col0  = c * 128;
    const int tid = threadIdx.x;
    const int w = tid >> 6, l = tid & 63;

    // A staging: wave w stages rows [32w, 32w+32) of the strip (2 gll x 16 rows x 64B)
    const int sub = l >> 2;
    const int swz = (((l & 3) ^ ((sub >> 1) & 3)) * 16);   // pre-swizzled source slot
    const int ra0 = strip * 128 + 32 * w + sub;
    const int ra1 = ra0 + 16;
    const int ba0 = ra0 >> 8, sa0 = ra0 & 255;
    const int ba1 = ra1 >> 8, sa1 = ra1 & 255;

    const int oA0 = (32 * w) * 64;
    const int oA1 = (32 * w + 16) * 64;
    char* pc = smem;            // current A buffer
    char* pn = smem + 8192;     // next A buffer

    const int wr = (w >> 1) * 64;    // wave row offset
    const int h  = w & 1;            // wave col half
    const int wc = h * 64;
    const int fm = l & 15;
    const int rslot = (((l >> 4) ^ ((fm >> 1) & 3)) * 16);  // read-side XOR (matches source swz)

    const char* bfi = wsb + OFF_BFI + (size_t)(c * 2 + h) * (48 * 4096) + l * 16;
    const char* bft = wsb + OFF_BFT + (size_t)(c * 2 + h) * (8 * 4096) + l * 16;

    f32x4 acc[4][4];
    const char *a0, *a1;

    auto LOADB = [&](bf16x8 (&dst)[4], const char* base, int kt) {
#pragma unroll
        for (int t = 0; t < 4; ++t)
            dst[t] = *(const bf16x8*)(base + (size_t)kt * 4096 + t * 1024);
    };
    auto STAGE = [&](char* buf) {
        GLL(a0, buf + oA0);
        GLL(a1, buf + oA1);
        a0 += 64; a1 += 64;
    };
    auto COMP = [&](const char* buf, const bf16x8 (&bfr)[4]) {
        bf16x8 af[4];
#pragma unroll
        for (int t = 0; t < 4; ++t)
            af[t] = *(const bf16x8*)(buf + (wr + t * 16 + fm) * 64 + rslot);
#pragma unroll
        for (int i = 0; i < 4; ++i)
#pragma unroll
            for (int j = 0; j < 4; ++j)
                acc[i][j] = __builtin_amdgcn_mfma_f32_16x16x32_bf16(af[i], bfr[j], acc[i][j], 0, 0, 0);
    };

    auto GEMM = [&](const char* bbase, int nk) {   // nk even
        bf16x8 bA[4], bB[4];
        LOADB(bA, bbase, 0);
        STAGE(pc);                                  // outstanding: 4B + 2A = 6
#pragma unroll 1
        for (int kt = 0; kt < nk; kt += 2) {
            STAGE(pn);                              // A(kt+1)
            LOADB(bB, bbase, kt + 1);               // B(kt+1)   -> 12 outstanding
            asm volatile("s_waitcnt vmcnt(6)" ::: "memory");  // A(kt),B(kt) landed
            __builtin_amdgcn_s_barrier();
            __builtin_amdgcn_s_setprio(1);
            COMP(pc, bA);
            __builtin_amdgcn_s_setprio(0);
            asm volatile("s_waitcnt lgkmcnt(0)" ::: "memory"); // my pc reads drained
            __builtin_amdgcn_s_barrier();                      // pc safe to overwrite
            if (kt + 2 < nk) {
                STAGE(pc);                          // A(kt+2)
                LOADB(bA, bbase, kt + 2);           // B(kt+2)   -> 12 outstanding
                asm volatile("s_waitcnt vmcnt(6)" ::: "memory");  // A(kt+1),B(kt+1) landed
            } else {
                asm volatile("s_waitcnt vmcnt(0)" ::: "memory");  // final drain
            }
            __builtin_amdgcn_s_barrier();
            __builtin_amdgcn_s_setprio(1);
            COMP(pn, bB);
            __builtin_amdgcn_s_setprio(0);
            asm volatile("s_waitcnt lgkmcnt(0)" ::: "memory");
            __builtin_amdgcn_s_barrier();
        }
    };

    // epilogue: C/D layout col = lane&15, row = (lane>>4)*4 + reg
    auto EPI = [&](int s_base, bool with_corr) {
        const float* bias = with_corr ? (const float*)(wsb + OFF_BI) : b1;
        const float* corr = (const float*)(wsb + OFF_CORR);   // [d][b*2+s]
        const int ocol = col0 + wc + fm;
        const int rq   = (l >> 4) * 4;
        float bv[4];
#pragma unroll
        for (int j = 0; j < 4; ++j) bv[j] = bias[ocol + j * 16];
#pragma unroll
        for (int i = 0; i < 4; ++i) {
#pragma unroll
            for (int r = 0; r < 4; ++r) {
                const int rr  = strip * 128 + wr + i * 16 + rq + r;
                const int ssl = rr & 255;
                const int bb  = rr >> 8;
                float* op = out + ((size_t)(bb * SDIM + s_base + ssl)) * DDIM + ocol;
                if (with_corr && ssl < 2) {
                    const float* cp = corr + (size_t)ocol * 128 + bb * 2 + ssl;
#pragma unroll
                    for (int j = 0; j < 4; ++j)
                        op[j * 16] = acc[i][j][r] + bv[j] + cp[(size_t)j * 16 * 128];
                } else {
#pragma unroll
                    for (int j = 0; j < 4; ++j)
                        op[j * 16] = acc[i][j][r] + bv[j];
                }
            }
        }
    };

    // ---- interior: A row r=(b,s) is Xp[b][s : s+6][:] flattened (im2col) ----
#pragma unroll
    for (int i = 0; i < 4; ++i)
#pragma unroll
        for (int j = 0; j < 4; ++j) acc[i][j] = (f32x4){0.f, 0.f, 0.f, 0.f};
    a0 = (const char*)(Xp + (size_t)(ba0 * SPAD + sa0) * EDIM) + swz;
    a1 = (const char*)(Xp + (size_t)(ba1 * SPAD + sa1) * EDIM) + swz;
    GEMM(bfi, 48);
    EPI(0, true);

    // ---- tail: s in [256,512), unigram only: A row = Xp[b][s+2][:] = X[b][s][:] ----
#pragma unroll
    for (int i = 0; i < 4; ++i)
#pragma unroll
        for (int j = 0; j < 4; ++j) acc[i][j] = (f32x4){0.f, 0.f, 0.f, 0.f};
    a0 = (const char*)(Xp + (size_t)(ba0 * SPAD + 258 + sa0) * EDIM) + swz;
    a1 = (const char*)(Xp + (size_t)(ba1 * SPAD + 258 + sa1) * EDIM) + swz;
    GEMM(bft, 8);
    EPI(256, false);
}

extern "C" void kernel_launch(void* const* d_in, const int* in_sizes, int n_in,
                              void* d_out, int out_size, void* d_ws, size_t ws_size,
                              hipStream_t stream)
{
    const float* X  = (const float*)d_in[0];
    const float* W1 = (const float*)d_in[1];
    const float* b1 = (const float*)d_in[2];
    const float* W2 = (const float*)d_in[3];
    const float* b2 = (const float*)d_in[4];
    const float* W3 = (const float*)d_in[5];
    const float* b3 = (const float*)d_in[6];
    const float* W4 = (const float*)d_in[7];
    const float* b4 = (const float*)d_in[8];
    float* out = (float*)d_out;
    char*  wsb = (char*)d_ws;

    prep_all<<<dim3(PREP_BLOCKS), dim3(256), 0, stream>>>(X, W1, b1, W2, b2, W3, b3, W4, b4, wsb);

    mega<<<dim3(512), dim3(256), 0, stream>>>(
        (const unsigned short*)(wsb + OFF_XP), wsb, b1, out);
}

// Round 6
// 163.340 us; speedup vs baseline: 1.0377x; 1.0377x over previous
//
#include <hip/hip_runtime.h>
#include <hip/hip_bf16.h>

// B=64, S=512, E=256, D=512
#define EDIM 256
#define SDIM 512
#define BDIM 64
#define DDIM 512
#define SPAD 514   // padded S rows per batch in Xp (2 zero rows at front)

// ws byte offsets
#define OFF_XP    0u           // bf16 [64][514][256]  = 16,842,752 B
#define OFF_BFI   16842752u    // bf16 frag-major interior weights = 1,572,864 B
                               //   addr = (((c*2+h)*48 + kt)*4 + t)*1024 + l*16 + j*2
                               //   holds G_int[d = c*128+h*64+t*16+(l&15)][k = kt*32+(l>>4)*8+j]
#define OFF_BFT   18415616u    // bf16 frag-major tail (W1) weights = 262,144 B (same scheme, 8 kt)
#define OFF_CORR  18677760u    // f32  [512][128]  (layout [d][b*2+s])
#define OFF_BI    18939904u    // f32  [512]

// prep grid partition
#define CVT_BLOCKS  4112       // 64*514*32 / 256
#define BF_BASE     4112       // + 448 frag blocks (384 interior + 64 tail)
#define CORR_BASE   4560       // + 4096 corr blocks (512 d x 8 b-chunks)
#define PREP_BLOCKS 8656

typedef __attribute__((ext_vector_type(8))) __bf16 bf16x8;
typedef __attribute__((ext_vector_type(4))) float  f32x4;
typedef __attribute__((ext_vector_type(8))) unsigned short ushort8v;

__device__ __forceinline__ unsigned short f2bf(float f) {
    unsigned int u = __float_as_uint(f);
    u = (u + 0x7fffu + ((u >> 16) & 1u)) >> 16;   // RNE
    return (unsigned short)u;
}

// ============ launch 1: cvt_pad + weight-fragment + edge-correction ============
__global__ __launch_bounds__(256) void prep_all(
    const float* __restrict__ X,
    const float* __restrict__ W1, const float* __restrict__ b1,
    const float* __restrict__ W2, const float* __restrict__ b2,
    const float* __restrict__ W3, const float* __restrict__ b3,
    const float* __restrict__ W4, const float* __restrict__ b4,
    char* __restrict__ wsb)
{
    const int tid = threadIdx.x;

    if (blockIdx.x < CVT_BLOCKS) {
        // ---- bf16 copy of X with 2 zero rows prepended per batch, 8 elem/thread ----
        unsigned short* Xp = (unsigned short*)(wsb + OFF_XP);
        const int i   = blockIdx.x * 256 + tid;    // [0, 64*514*32)
        const int row = i >> 5;                    // b*514 + j
        const int q   = i & 31;                    // 8-elem group
        const int b   = row / SPAD;
        const int j   = row - b * SPAD;
        ushort8v v;
        if (j < 2) {
            v = (ushort8v)0;
        } else {
            const float* src = X + ((size_t)(b * SDIM + j - 2)) * EDIM + q * 8;
            const float4 f0 = *(const float4*)(src);
            const float4 f1 = *(const float4*)(src + 4);
            v[0] = f2bf(f0.x); v[1] = f2bf(f0.y); v[2] = f2bf(f0.z); v[3] = f2bf(f0.w);
            v[4] = f2bf(f1.x); v[5] = f2bf(f1.y); v[6] = f2bf(f1.z); v[7] = f2bf(f1.w);
        }
        *(ushort8v*)(Xp + (size_t)row * EDIM + q * 8) = v;
        return;
    }

    if (blockIdx.x < CORR_BASE) {
        // ---- combined weights in FRAGMENT-MAJOR layout (direct MFMA B-operand) ----
        // G_int[d][k], k = shift*256 + e, shift 0..5 (delta grouping, R0 derivation):
        //   s0: w40 | s1: w30+w40+w41 | s2: w1+w20+w30+w31+w40+w41+w42
        //   s3: w21+w31+w32+w41+w42+w43 | s4: w32+w42+w43 | s5: w43
        const int p  = blockIdx.x - BF_BASE;   // 0..447
        const int t  = tid >> 6;
        const int l  = tid & 63;
        const int fm = l & 15;
        const int hi = l >> 4;
        if (p < 384) {
            const int kt = p % 48;             // shift = kt>>3 is block-uniform
            const int h  = (p / 48) & 1;
            const int c  = p / 96;
            const int d  = c * 128 + h * 64 + t * 16 + fm;
            const int shift = kt >> 3;
            const int e0 = (kt & 7) * 32 + hi * 8;
            ushort8v v;
#pragma unroll
            for (int j = 0; j < 8; ++j) {
                const int e  = e0 + j;
                const int de = d * 256 + e;
                float g;
                if      (shift == 0) g = W4[de*4+0];
                else if (shift == 1) g = W3[de*3+0] + W4[de*4+0] + W4[de*4+1];
                else if (shift == 2) g = W1[de] + W2[de*2+0] + W3[de*3+0] + W3[de*3+1]
                                       + W4[de*4+0] + W4[de*4+1] + W4[de*4+2];
                else if (shift == 3) g = W2[de*2+1] + W3[de*3+1] + W3[de*3+2]
                                       + W4[de*4+1] + W4[de*4+2] + W4[de*4+3];
                else if (shift == 4) g = W3[de*3+2] + W4[de*4+2] + W4[de*4+3];
                else                 g = W4[de*4+3];
                v[j] = f2bf(g);
            }
            *(ushort8v*)(wsb + OFF_BFI + (size_t)((((c*2+h)*48 + kt)*4 + t)*1024 + l*16)) = v;
            if (kt == 0 && hi == 0)   // one lane per d
                ((float*)(wsb + OFF_BI))[d] = b1[d] + b2[d] + 2.0f*b3[d] + 3.0f*b4[d];
        } else {
            const int q  = p - 384;
            const int kt = q % 8;
            const int h  = (q / 8) & 1;
            const int c  = q / 16;
            const int d  = c * 128 + h * 64 + t * 16 + fm;
            const int k0 = kt * 32 + hi * 8;
            ushort8v v;
#pragma unroll
            for (int j = 0; j < 8; ++j) v[j] = f2bf(W1[d * 256 + k0 + j]);
            *(ushort8v*)(wsb + OFF_BFT + (size_t)((((c*2+h)*8 + kt)*4 + t)*1024 + l*16)) = v;
        }
        return;
    }

    // ---- edge correction, block = (d, 8-batch chunk); coalesced weight rows.
    {
        __shared__ float cls[16];
        const int cb = blockIdx.x - CORR_BASE;   // 0..4095
        const int d  = cb >> 3;                  // 0..511
        const int bq = (cb & 7) * 8;             // batch chunk base
        const int e  = tid;                      // 0..255

        if (tid < 16) cls[tid] = 0.f;

        const float w31 = W3[(size_t)d * 768 + 3 * e + 1];
        const float w32 = W3[(size_t)d * 768 + 3 * e + 2];
        const float4 w4v = *(const float4*)(W4 + (size_t)d * 1024 + 4 * e);
        const float w41 = w4v.y, w42 = w4v.z, w43 = w4v.w;

        const float c00 = w31 + w41 + w42;
        const float c01 = w32 + w42 + w43;
        const float c02 = w43;
        __syncthreads();

#pragma unroll
        for (int bi = 0; bi < 8; ++bi) {
            const float* xr = X + (size_t)(bq + bi) * (SDIM * EDIM) + e;
            const float x0 = xr[0], x1 = xr[EDIM], x2 = xr[2 * EDIM];
            float a0 = c00 * x0 + c01 * x1 + c02 * x2;
            float a1 = w41 * x0 + w42 * x1 + w43 * x2;
#pragma unroll
            for (int off = 32; off >= 1; off >>= 1) {
                a0 += __shfl_xor(a0, off, 64);
                a1 += __shfl_xor(a1, off, 64);
            }
            if ((tid & 63) == 0) {
                atomicAdd(&cls[bi * 2 + 0], a0);
                atomicAdd(&cls[bi * 2 + 1], a1);
            }
        }
        __syncthreads();

        if (tid < 16) {
            const int s = tid & 1;
            const float bc = s ? b4[d] : (b3[d] + 2.f * b4[d]);
            ((float*)(wsb + OFF_CORR))[(size_t)d * 128 + bq * 2 + tid] = -cls[tid] - bc;
        }
    }
}

// ============ launch 2: paired GEMM, A-only LDS, B in registers ============
// 512 blocks: interior 128x128 tile (K=1536) then same strip's tail (K=256).
// R4 fix: NATURAL block id (no swizzle). Strip s's 4 col-blocks are ids
// {s, s+128, s+256, s+384} == s (mod 8) -> SAME XCD, co-resident (2 blk/CU
// x 32 CU = 64 = all of an XCD's blocks) -> A k-tiles read in near-lockstep,
// Xp fetched ~once from HBM. R3's swizzle put them on 4 XCDs -> 4x Xp fetch
// (FETCH 72MB, +5us). B panels (1.75MB) replicate per-XCD via L2 trivially.
#define GLL(src, dst) \
    __builtin_amdgcn_global_load_lds((const __attribute__((address_space(1))) void*)(src), \
                                     (__attribute__((address_space(3))) void*)(dst), 16, 0, 0)

__global__ __launch_bounds__(256) void mega(
    const unsigned short* __restrict__ Xp,
    const char* __restrict__ wsb,
    const float* __restrict__ b1,
    float* __restrict__ out)
{
    __shared__ __align__(16) char smem[16384];   // 2 x 8KB A buffers
    const int id  = blockIdx.x;                  // natural: XCD = id%8, strip%8 == id%8
    const int strip = id & 127;                  // 128 strips x 128 rows
    const int c     = id >> 7;                   // col block 0..3
    const int col0  = c * 128;
    const int tid = threadIdx.x;
    const int w = tid >> 6, l = tid & 63;

    // A staging: wave w stages rows [32w, 32w+32) of the strip (2 gll x 16 rows x 64B)
    const int sub = l >> 2;
    const int swz = (((l & 3) ^ ((sub >> 1) & 3)) * 16);   // pre-swizzled source slot
    const int ra0 = strip * 128 + 32 * w + sub;
    const int ra1 = ra0 + 16;
    const int ba0 = ra0 >> 8, sa0 = ra0 & 255;
    const int ba1 = ra1 >> 8, sa1 = ra1 & 255;

    const int oA0 = (32 * w) * 64;
    const int oA1 = (32 * w + 16) * 64;
    char* pc = smem;            // current A buffer
    char* pn = smem + 8192;     // next A buffer

    const int wr = (w >> 1) * 64;    // wave row offset
    const int h  = w & 1;            // wave col half
    const int wc = h * 64;
    const int fm = l & 15;
    const int rslot = (((l >> 4) ^ ((fm >> 1) & 3)) * 16);  // read-side XOR (matches source swz)

    const char* bfi = wsb + OFF_BFI + (size_t)(c * 2 + h) * (48 * 4096) + l * 16;
    const char* bft = wsb + OFF_BFT + (size_t)(c * 2 + h) * (8 * 4096) + l * 16;

    f32x4 acc[4][4];
    const char *a0, *a1;

    auto LOADB = [&](bf16x8 (&dst)[4], const char* base, int kt) {
#pragma unroll
        for (int t = 0; t < 4; ++t)
            dst[t] = *(const bf16x8*)(base + (size_t)kt * 4096 + t * 1024);
    };
    auto STAGE = [&](char* buf) {
        GLL(a0, buf + oA0);
        GLL(a1, buf + oA1);
        a0 += 64; a1 += 64;
    };
    auto COMP = [&](const char* buf, const bf16x8 (&bfr)[4]) {
        bf16x8 af[4];
#pragma unroll
        for (int t = 0; t < 4; ++t)
            af[t] = *(const bf16x8*)(buf + (wr + t * 16 + fm) * 64 + rslot);
#pragma unroll
        for (int i = 0; i < 4; ++i)
#pragma unroll
            for (int j = 0; j < 4; ++j)
                acc[i][j] = __builtin_amdgcn_mfma_f32_16x16x32_bf16(af[i], bfr[j], acc[i][j], 0, 0, 0);
    };

    auto GEMM = [&](const char* bbase, int nk) {   // nk even
        bf16x8 bA[4], bB[4];
        LOADB(bA, bbase, 0);
        STAGE(pc);                                  // outstanding: 4B + 2A = 6
#pragma unroll 1
        for (int kt = 0; kt < nk; kt += 2) {
            STAGE(pn);                              // A(kt+1)
            LOADB(bB, bbase, kt + 1);               // B(kt+1)   -> 12 outstanding
            asm volatile("s_waitcnt vmcnt(6)" ::: "memory");  // A(kt),B(kt) landed
            __builtin_amdgcn_s_barrier();
            __builtin_amdgcn_s_setprio(1);
            COMP(pc, bA);
            __builtin_amdgcn_s_setprio(0);
            asm volatile("s_waitcnt lgkmcnt(0)" ::: "memory"); // my pc reads drained
            __builtin_amdgcn_s_barrier();                      // pc safe to overwrite
            if (kt + 2 < nk) {
                STAGE(pc);                          // A(kt+2)
                LOADB(bA, bbase, kt + 2);           // B(kt+2)   -> 12 outstanding
                asm volatile("s_waitcnt vmcnt(6)" ::: "memory");  // A(kt+1),B(kt+1) landed
            } else {
                asm volatile("s_waitcnt vmcnt(0)" ::: "memory");  // final drain
            }
            __builtin_amdgcn_s_barrier();
            __builtin_amdgcn_s_setprio(1);
            COMP(pn, bB);
            __builtin_amdgcn_s_setprio(0);
            asm volatile("s_waitcnt lgkmcnt(0)" ::: "memory");
            __builtin_amdgcn_s_barrier();
        }
    };

    // epilogue: C/D layout col = lane&15, row = (lane>>4)*4 + reg
    auto EPI = [&](int s_base, bool with_corr) {
        const float* bias = with_corr ? (const float*)(wsb + OFF_BI) : b1;
        const float* corr = (const float*)(wsb + OFF_CORR);   // [d][b*2+s]
        const int ocol = col0 + wc + fm;
        const int rq   = (l >> 4) * 4;
        float bv[4];
#pragma unroll
        for (int j = 0; j < 4; ++j) bv[j] = bias[ocol + j * 16];
#pragma unroll
        for (int i = 0; i < 4; ++i) {
#pragma unroll
            for (int r = 0; r < 4; ++r) {
                const int rr  = strip * 128 + wr + i * 16 + rq + r;
                const int ssl = rr & 255;
                const int bb  = rr >> 8;
                float* op = out + ((size_t)(bb * SDIM + s_base + ssl)) * DDIM + ocol;
                if (with_corr && ssl < 2) {
                    const float* cp = corr + (size_t)ocol * 128 + bb * 2 + ssl;
#pragma unroll
                    for (int j = 0; j < 4; ++j)
                        op[j * 16] = acc[i][j][r] + bv[j] + cp[(size_t)j * 16 * 128];
                } else {
#pragma unroll
                    for (int j = 0; j < 4; ++j)
                        op[j * 16] = acc[i][j][r] + bv[j];
                }
            }
        }
    };

    // ---- interior: A row r=(b,s) is Xp[b][s : s+6][:] flattened (im2col) ----
#pragma unroll
    for (int i = 0; i < 4; ++i)
#pragma unroll
        for (int j = 0; j < 4; ++j) acc[i][j] = (f32x4){0.f, 0.f, 0.f, 0.f};
    a0 = (const char*)(Xp + (size_t)(ba0 * SPAD + sa0) * EDIM) + swz;
    a1 = (const char*)(Xp + (size_t)(ba1 * SPAD + sa1) * EDIM) + swz;
    GEMM(bfi, 48);
    EPI(0, true);

    // ---- tail: s in [256,512), unigram only: A row = Xp[b][s+2][:] = X[b][s][:] ----
#pragma unroll
    for (int i = 0; i < 4; ++i)
#pragma unroll
        for (int j = 0; j < 4; ++j) acc[i][j] = (f32x4){0.f, 0.f, 0.f, 0.f};
    a0 = (const char*)(Xp + (size_t)(ba0 * SPAD + 258 + sa0) * EDIM) + swz;
    a1 = (const char*)(Xp + (size_t)(ba1 * SPAD + 258 + sa1) * EDIM) + swz;
    GEMM(bft, 8);
    EPI(256, false);
}

extern "C" void kernel_launch(void* const* d_in, const int* in_sizes, int n_in,
                              void* d_out, int out_size, void* d_ws, size_t ws_size,
                              hipStream_t stream)
{
    const float* X  = (const float*)d_in[0];
    const float* W1 = (const float*)d_in[1];
    const float* b1 = (const float*)d_in[2];
    const float* W2 = (const float*)d_in[3];
    const float* b2 = (const float*)d_in[4];
    const float* W3 = (const float*)d_in[5];
    const float* b3 = (const float*)d_in[6];
    const float* W4 = (const float*)d_in[7];
    const float* b4 = (const float*)d_in[8];
    float* out = (float*)d_out;
    char*  wsb = (char*)d_ws;

    prep_all<<<dim3(PREP_BLOCKS), dim3(256), 0, stream>>>(X, W1, b1, W2, b2, W3, b3, W4, b4, wsb);

    mega<<<dim3(512), dim3(256), 0, stream>>>(
        (const unsigned short*)(wsb + OFF_XP), wsb, b1, out);
}

// Round 7
// 160.306 us; speedup vs baseline: 1.0574x; 1.0189x over previous
//
#include <hip/hip_runtime.h>
#include <hip/hip_bf16.h>

// B=64, S=512, E=256, D=512
#define EDIM 256
#define SDIM 512
#define BDIM 64
#define DDIM 512
#define SPAD 514   // padded S rows per batch in Xp (2 zero rows at front)

// ws byte offsets
#define OFF_XP    0u           // bf16 [64][514][256]  = 16,842,752 B
#define OFF_BFI   16842752u    // bf16 frag-major interior weights = 1,572,864 B
                               //   addr = ((c*2+h)*48 + kt)*4096 + t*1024 + hi*256 + fm*16 + j*2
                               //   holds G_int[d = c*128+h*64+t*16+fm][k = kt*32 + hi*8 + j]
#define OFF_BFT   18415616u    // bf16 frag-major tail (W1) weights = 262,144 B (same scheme, 8 kt)
#define OFF_CORR  18677760u    // f32  [512][128]  (layout [d][b*2+s])
#define OFF_BI    18939904u    // f32  [512]

// prep grid partition (R7: frag pass back to 512 coalesced-read per-d blocks)
#define CVT_BLOCKS  4112       // 64*514*32 / 256
#define WB_BASE     4112       // + 512 weight blocks (one per d)
#define CORR_BASE   4624       // + 4096 corr blocks (512 d x 8 b-chunks)
#define PREP_BLOCKS 8720

typedef __attribute__((ext_vector_type(8))) __bf16 bf16x8;
typedef __attribute__((ext_vector_type(4))) float  f32x4;
typedef __attribute__((ext_vector_type(8))) unsigned short ushort8v;

__device__ __forceinline__ unsigned short f2bf(float f) {
    unsigned int u = __float_as_uint(f);
    u = (u + 0x7fffu + ((u >> 16) & 1u)) >> 16;   // RNE
    return (unsigned short)u;
}

// ============ launch 1: cvt_pad + weight-fragment + edge-correction ============
__global__ __launch_bounds__(256) void prep_all(
    const float* __restrict__ X,
    const float* __restrict__ W1, const float* __restrict__ b1,
    const float* __restrict__ W2, const float* __restrict__ b2,
    const float* __restrict__ W3, const float* __restrict__ b3,
    const float* __restrict__ W4, const float* __restrict__ b4,
    char* __restrict__ wsb)
{
    const int tid = threadIdx.x;

    if (blockIdx.x < CVT_BLOCKS) {
        // ---- bf16 copy of X with 2 zero rows prepended per batch, 8 elem/thread ----
        unsigned short* Xp = (unsigned short*)(wsb + OFF_XP);
        const int i   = blockIdx.x * 256 + tid;    // [0, 64*514*32)
        const int row = i >> 5;                    // b*514 + j
        const int q   = i & 31;                    // 8-elem group
        const int b   = row / SPAD;
        const int j   = row - b * SPAD;
        ushort8v v;
        if (j < 2) {
            v = (ushort8v)0;
        } else {
            const float* src = X + ((size_t)(b * SDIM + j - 2)) * EDIM + q * 8;
            const float4 f0 = *(const float4*)(src);
            const float4 f1 = *(const float4*)(src + 4);
            v[0] = f2bf(f0.x); v[1] = f2bf(f0.y); v[2] = f2bf(f0.z); v[3] = f2bf(f0.w);
            v[4] = f2bf(f1.x); v[5] = f2bf(f1.y); v[6] = f2bf(f1.z); v[7] = f2bf(f1.w);
        }
        *(ushort8v*)(Xp + (size_t)row * EDIM + q * 8) = v;
        return;
    }

    if (blockIdx.x < CORR_BASE) {
        // ---- combined weights -> fragment-major, one block per d (coalesced reads) ----
        // G_int[d][k], k = shift*256 + e, shift 0..5 (delta grouping, R0 derivation):
        //   s0: w40 | s1: w30+w40+w41 | s2: w1+w20+w30+w31+w40+w41+w42
        //   s3: w21+w31+w32+w41+w42+w43 | s4: w32+w42+w43 | s5: w43
        // Frag addr for (d,k): kt=k>>5; hi=(k>>3)&3; j=k&7; fm=d&15; t=(d>>4)&3;
        //   h=(d>>6)&1; c=d>>7; byte = ((c*2+h)*48+kt)*4096 + t*1024 + hi*256 + fm*16 + j*2
        const int d = blockIdx.x - WB_BASE;  // 0..511
        const int e = tid;                   // 0..255
        const int de = d * EDIM + e;

        const float w1  = W1[de];
        const float w20 = W2[de * 2 + 0], w21 = W2[de * 2 + 1];
        const float w30 = W3[de * 3 + 0], w31 = W3[de * 3 + 1], w32 = W3[de * 3 + 2];
        const float w40 = W4[de * 4 + 0], w41 = W4[de * 4 + 1], w42 = W4[de * 4 + 2], w43 = W4[de * 4 + 3];

        float g[6];
        g[0] = w40;
        g[1] = w30 + w40 + w41;
        g[2] = w1 + w20 + w30 + w31 + w40 + w41 + w42;
        g[3] = w21 + w31 + w32 + w41 + w42 + w43;
        g[4] = w32 + w42 + w43;
        g[5] = w43;

        const int fm = d & 15, t = (d >> 4) & 3, h = (d >> 6) & 1, c = d >> 7;
        const int hi = (e >> 3) & 3, j = e & 7, eb = e >> 5;
        char* ibase = wsb + OFF_BFI + (size_t)((c * 2 + h) * 48) * 4096
                    + t * 1024 + hi * 256 + fm * 16 + j * 2;
#pragma unroll
        for (int s = 0; s < 6; ++s)
            *(unsigned short*)(ibase + (size_t)(s * 8 + eb) * 4096) = f2bf(g[s]);

        *(unsigned short*)(wsb + OFF_BFT + (size_t)((c * 2 + h) * 8 + eb) * 4096
                           + t * 1024 + hi * 256 + fm * 16 + j * 2) = f2bf(w1);

        if (e == 0)
            ((float*)(wsb + OFF_BI))[d] = b1[d] + b2[d] + 2.0f * b3[d] + 3.0f * b4[d];
        return;
    }

    // ---- edge correction, block = (d, 8-batch chunk); coalesced weight rows.
    {
        __shared__ float cls[16];
        const int cb = blockIdx.x - CORR_BASE;   // 0..4095
        const int d  = cb >> 3;                  // 0..511
        const int bq = (cb & 7) * 8;             // batch chunk base
        const int e  = tid;                      // 0..255

        if (tid < 16) cls[tid] = 0.f;

        const float w31 = W3[(size_t)d * 768 + 3 * e + 1];
        const float w32 = W3[(size_t)d * 768 + 3 * e + 2];
        const float4 w4v = *(const float4*)(W4 + (size_t)d * 1024 + 4 * e);
        const float w41 = w4v.y, w42 = w4v.z, w43 = w4v.w;

        const float c00 = w31 + w41 + w42;
        const float c01 = w32 + w42 + w43;
        const float c02 = w43;
        __syncthreads();

#pragma unroll
        for (int bi = 0; bi < 8; ++bi) {
            const float* xr = X + (size_t)(bq + bi) * (SDIM * EDIM) + e;
            const float x0 = xr[0], x1 = xr[EDIM], x2 = xr[2 * EDIM];
            float a0 = c00 * x0 + c01 * x1 + c02 * x2;
            float a1 = w41 * x0 + w42 * x1 + w43 * x2;
#pragma unroll
            for (int off = 32; off >= 1; off >>= 1) {
                a0 += __shfl_xor(a0, off, 64);
                a1 += __shfl_xor(a1, off, 64);
            }
            if ((tid & 63) == 0) {
                atomicAdd(&cls[bi * 2 + 0], a0);
                atomicAdd(&cls[bi * 2 + 1], a1);
            }
        }
        __syncthreads();

        if (tid < 16) {
            const int s = tid & 1;
            const float bc = s ? b4[d] : (b3[d] + 2.f * b4[d]);
            ((float*)(wsb + OFF_CORR))[(size_t)d * 128 + bq * 2 + tid] = -cls[tid] - bc;
        }
    }
}

// ============ launch 2: depth-2 pipelined GEMM, A-only LDS, B in registers ============
// 512 blocks (natural id, same-XCD col-blocks: FETCH 19MB verified R6):
// interior 128x128 (K=1536) then same strip's tail (K=256).
// R7 schedule: 4 A-buffers (4x8KB) + 4 B register sets; loads for step kt+2
// issued at step kt -> 2 full COMPs of latency tolerance (>600cyc > L2 RT).
// ONE barrier per step (R1's proven placement): each phase-top lgkmcnt(0)
// drains my previous phase's ds_reads BEFORE the join, so by the barrier at
// phase p every wave is done reading buffer (p-1); the STAGE at phase p
// targets buffer (p+2)%4 == (p-2)%4, last read at phase p-2 -> protected by
// the barrier at p-1. vmcnt(6) = one 6-load set (kt+1's) in flight across
// every barrier; never drained to 0 in-loop.
#define GLL(src, dst) \
    __builtin_amdgcn_global_load_lds((const __attribute__((address_space(1))) void*)(src), \
                                     (__attribute__((address_space(3))) void*)(dst), 16, 0, 0)

__global__ __launch_bounds__(256, 2) void mega(
    const unsigned short* __restrict__ Xp,
    const char* __restrict__ wsb,
    const float* __restrict__ b1,
    float* __restrict__ out)
{
    __shared__ __align__(16) char smem[32768];   // 4 x 8KB A buffers
    const int id  = blockIdx.x;                  // natural: XCD = id%8 = strip%8
    const int strip = id & 127;                  // 128 strips x 128 rows
    const int c     = id >> 7;                   // col block 0..3
    const int col0  = c * 128;
    const int tid = threadIdx.x;
    const int w = tid >> 6, l = tid & 63;

    // A staging: wave w stages rows [32w, 32w+32) of the strip (2 gll x 16 rows x 64B)
    const int sub = l >> 2;
    const int swz = (((l & 3) ^ ((sub >> 1) & 3)) * 16);   // pre-swizzled source slot
    const int ra0 = strip * 128 + 32 * w + sub;
    const int ra1 = ra0 + 16;
    const int ba0 = ra0 >> 8, sa0 = ra0 & 255;
    const int ba1 = ra1 >> 8, sa1 = ra1 & 255;

    const int oA0 = (32 * w) * 64;
    const int oA1 = (32 * w + 16) * 64;
    char* q0 = smem;
    char* q1 = smem + 8192;
    char* q2 = smem + 16384;
    char* q3 = smem + 24576;

    const int wr = (w >> 1) * 64;    // wave row offset
    const int h  = w & 1;            // wave col half
    const int wc = h * 64;
    const int fm = l & 15;
    const int rslot = (((l >> 4) ^ ((fm >> 1) & 3)) * 16);  // read-side XOR (matches source swz)

    const char* bfi = wsb + OFF_BFI + (size_t)(c * 2 + h) * (48 * 4096) + l * 16;
    const char* bft = wsb + OFF_BFT + (size_t)(c * 2 + h) * (8 * 4096) + l * 16;

    f32x4 acc[4][4];
    const char *a0, *a1;

    auto LOADB = [&](bf16x8 (&dst)[4], const char* base, int kt) {
#pragma unroll
        for (int t = 0; t < 4; ++t)
            dst[t] = *(const bf16x8*)(base + (size_t)kt * 4096 + t * 1024);
    };
    auto STAGE = [&](char* buf) {
        GLL(a0, buf + oA0);
        GLL(a1, buf + oA1);
        a0 += 64; a1 += 64;
    };
    auto COMP = [&](const char* buf, const bf16x8 (&bfr)[4]) {
        bf16x8 af[4];
#pragma unroll
        for (int t = 0; t < 4; ++t)
            af[t] = *(const bf16x8*)(buf + (wr + t * 16 + fm) * 64 + rslot);
#pragma unroll
        for (int i = 0; i < 4; ++i)
#pragma unroll
            for (int j = 0; j < 4; ++j)
                acc[i][j] = __builtin_amdgcn_mfma_f32_16x16x32_bf16(af[i], bfr[j], acc[i][j], 0, 0, 0);
    };

#define PHASE_W6  asm volatile("s_waitcnt vmcnt(6) lgkmcnt(0)" ::: "memory"); \
                  __builtin_amdgcn_s_barrier();
#define PHASE_W0  asm volatile("s_waitcnt vmcnt(0) lgkmcnt(0)" ::: "memory"); \
                  __builtin_amdgcn_s_barrier();
#define DO_COMP(Q, B) __builtin_amdgcn_s_setprio(1); COMP(Q, B); __builtin_amdgcn_s_setprio(0);

    auto GEMM = [&](const char* bbase, int nk) {   // nk % 4 == 0, nk >= 8
        bf16x8 b0[4], b1r[4], b2[4], b3[4];
        STAGE(q0); LOADB(b0,  bbase, 0);
        STAGE(q1); LOADB(b1r, bbase, 1);
#pragma unroll 1
        for (int kt = 0; kt + 4 < nk; kt += 4) {
            PHASE_W6; STAGE(q2); LOADB(b2,  bbase, kt + 2); DO_COMP(q0, b0);
            PHASE_W6; STAGE(q3); LOADB(b3,  bbase, kt + 3); DO_COMP(q1, b1r);
            PHASE_W6; STAGE(q0); LOADB(b0,  bbase, kt + 4); DO_COMP(q2, b2);
            PHASE_W6; STAGE(q1); LOADB(b1r, bbase, kt + 5); DO_COMP(q3, b3);
        }
        // final 4 phases (kt = nk-4): stage only nk-2, nk-1
        PHASE_W6; STAGE(q2); LOADB(b2, bbase, nk - 2); DO_COMP(q0, b0);
        PHASE_W6; STAGE(q3); LOADB(b3, bbase, nk - 1); DO_COMP(q1, b1r);
        PHASE_W6;                                      DO_COMP(q2, b2);
        PHASE_W0;                                      DO_COMP(q3, b3);
    };

    // epilogue: C/D layout col = lane&15, row = (lane>>4)*4 + reg
    auto EPI = [&](int s_base, bool with_corr) {
        const float* bias = with_corr ? (const float*)(wsb + OFF_BI) : b1;
        const float* corr = (const float*)(wsb + OFF_CORR);   // [d][b*2+s]
        const int ocol = col0 + wc + fm;
        const int rq   = (l >> 4) * 4;
        float bv[4];
#pragma unroll
        for (int j = 0; j < 4; ++j) bv[j] = bias[ocol + j * 16];
#pragma unroll
        for (int i = 0; i < 4; ++i) {
#pragma unroll
            for (int r = 0; r < 4; ++r) {
                const int rr  = strip * 128 + wr + i * 16 + rq + r;
                const int ssl = rr & 255;
                const int bb  = rr >> 8;
                float* op = out + ((size_t)(bb * SDIM + s_base + ssl)) * DDIM + ocol;
                if (with_corr && ssl < 2) {
                    const float* cp = corr + (size_t)ocol * 128 + bb * 2 + ssl;
#pragma unroll
                    for (int j = 0; j < 4; ++j)
                        op[j * 16] = acc[i][j][r] + bv[j] + cp[(size_t)j * 16 * 128];
                } else {
#pragma unroll
                    for (int j = 0; j < 4; ++j)
                        op[j * 16] = acc[i][j][r] + bv[j];
                }
            }
        }
    };

    // ---- interior: A row r=(b,s) is Xp[b][s : s+6][:] flattened (im2col) ----
#pragma unroll
    for (int i = 0; i < 4; ++i)
#pragma unroll
        for (int j = 0; j < 4; ++j) acc[i][j] = (f32x4){0.f, 0.f, 0.f, 0.f};
    a0 = (const char*)(Xp + (size_t)(ba0 * SPAD + sa0) * EDIM) + swz;
    a1 = (const char*)(Xp + (size_t)(ba1 * SPAD + sa1) * EDIM) + swz;
    GEMM(bfi, 48);
    EPI(0, true);

    // ---- tail: s in [256,512), unigram only: A row = Xp[b][s+2][:] = X[b][s][:] ----
#pragma unroll
    for (int i = 0; i < 4; ++i)
#pragma unroll
        for (int j = 0; j < 4; ++j) acc[i][j] = (f32x4){0.f, 0.f, 0.f, 0.f};
    a0 = (const char*)(Xp + (size_t)(ba0 * SPAD + 258 + sa0) * EDIM) + swz;
    a1 = (const char*)(Xp + (size_t)(ba1 * SPAD + 258 + sa1) * EDIM) + swz;
    GEMM(bft, 8);
    EPI(256, false);
}

extern "C" void kernel_launch(void* const* d_in, const int* in_sizes, int n_in,
                              void* d_out, int out_size, void* d_ws, size_t ws_size,
                              hipStream_t stream)
{
    const float* X  = (const float*)d_in[0];
    const float* W1 = (const float*)d_in[1];
    const float* b1 = (const float*)d_in[2];
    const float* W2 = (const float*)d_in[3];
    const float* b2 = (const float*)d_in[4];
    const float* W3 = (const float*)d_in[5];
    const float* b3 = (const float*)d_in[6];
    const float* W4 = (const float*)d_in[7];
    const float* b4 = (const float*)d_in[8];
    float* out = (float*)d_out;
    char*  wsb = (char*)d_ws;

    prep_all<<<dim3(PREP_BLOCKS), dim3(256), 0, stream>>>(X, W1, b1, W2, b2, W3, b3, W4, b4, wsb);

    mega<<<dim3(512), dim3(256), 0, stream>>>(
        (const unsigned short*)(wsb + OFF_XP), wsb, b1, out);
}

// Round 8
// 159.528 us; speedup vs baseline: 1.0625x; 1.0049x over previous
//
#include <hip/hip_runtime.h>
#include <hip/hip_bf16.h>

// B=64, S=512, E=256, D=512
#define EDIM 256
#define SDIM 512
#define BDIM 64
#define DDIM 512
#define SPAD 514   // padded S rows per batch in Xp (2 zero rows at front)

// ws byte offsets
#define OFF_XP    0u           // bf16 [64][514][256]  = 16,842,752 B
#define OFF_BFI   16842752u    // bf16 frag-major interior weights = 1,572,864 B
                               //   addr = ((c*2+h)*48 + kt)*4096 + t*1024 + hi*256 + fm*16 + j*2
                               //   holds G_int[d = c*128+h*64+t*16+fm][k = kt*32 + hi*8 + j]
#define OFF_BFT   18415616u    // bf16 frag-major tail (W1) weights = 262,144 B (same scheme, 8 kt)
#define OFF_CORR  18677760u    // f32  [512][128]  (layout [d][b*2+s])
#define OFF_BI    18939904u    // f32  [512]

// prep grid partition
#define CVT_BLOCKS  4112       // 64*514*32 / 256
#define WB_BASE     4112       // + 512 weight blocks (one per d)
#define CORR_BASE   4624       // + 4096 corr blocks (512 d x 8 b-chunks)
#define PREP_BLOCKS 8720

typedef __attribute__((ext_vector_type(8))) __bf16 bf16x8;
typedef __attribute__((ext_vector_type(4))) float  f32x4;
typedef __attribute__((ext_vector_type(8))) unsigned short ushort8v;

__device__ __forceinline__ unsigned short f2bf(float f) {
    unsigned int u = __float_as_uint(f);
    u = (u + 0x7fffu + ((u >> 16) & 1u)) >> 16;   // RNE
    return (unsigned short)u;
}

// ============ launch 1: cvt_pad + weight-fragment + edge-correction ============
__global__ __launch_bounds__(256) void prep_all(
    const float* __restrict__ X,
    const float* __restrict__ W1, const float* __restrict__ b1,
    const float* __restrict__ W2, const float* __restrict__ b2,
    const float* __restrict__ W3, const float* __restrict__ b3,
    const float* __restrict__ W4, const float* __restrict__ b4,
    char* __restrict__ wsb)
{
    const int tid = threadIdx.x;

    if (blockIdx.x < CVT_BLOCKS) {
        // ---- bf16 copy of X with 2 zero rows prepended per batch, 8 elem/thread ----
        unsigned short* Xp = (unsigned short*)(wsb + OFF_XP);
        const int i   = blockIdx.x * 256 + tid;    // [0, 64*514*32)
        const int row = i >> 5;                    // b*514 + j
        const int q   = i & 31;                    // 8-elem group
        const int b   = row / SPAD;
        const int j   = row - b * SPAD;
        ushort8v v;
        if (j < 2) {
            v = (ushort8v)0;
        } else {
            const float* src = X + ((size_t)(b * SDIM + j - 2)) * EDIM + q * 8;
            const float4 f0 = *(const float4*)(src);
            const float4 f1 = *(const float4*)(src + 4);
            v[0] = f2bf(f0.x); v[1] = f2bf(f0.y); v[2] = f2bf(f0.z); v[3] = f2bf(f0.w);
            v[4] = f2bf(f1.x); v[5] = f2bf(f1.y); v[6] = f2bf(f1.z); v[7] = f2bf(f1.w);
        }
        *(ushort8v*)(Xp + (size_t)row * EDIM + q * 8) = v;
        return;
    }

    if (blockIdx.x < CORR_BASE) {
        // ---- combined weights -> fragment-major, one block per d (coalesced reads) ----
        // G_int[d][k], k = shift*256 + e, shift 0..5 (delta grouping, R0 derivation):
        //   s0: w40 | s1: w30+w40+w41 | s2: w1+w20+w30+w31+w40+w41+w42
        //   s3: w21+w31+w32+w41+w42+w43 | s4: w32+w42+w43 | s5: w43
        const int d = blockIdx.x - WB_BASE;  // 0..511
        const int e = tid;                   // 0..255
        const int de = d * EDIM + e;

        const float w1  = W1[de];
        const float w20 = W2[de * 2 + 0], w21 = W2[de * 2 + 1];
        const float w30 = W3[de * 3 + 0], w31 = W3[de * 3 + 1], w32 = W3[de * 3 + 2];
        const float w40 = W4[de * 4 + 0], w41 = W4[de * 4 + 1], w42 = W4[de * 4 + 2], w43 = W4[de * 4 + 3];

        float g[6];
        g[0] = w40;
        g[1] = w30 + w40 + w41;
        g[2] = w1 + w20 + w30 + w31 + w40 + w41 + w42;
        g[3] = w21 + w31 + w32 + w41 + w42 + w43;
        g[4] = w32 + w42 + w43;
        g[5] = w43;

        const int fm = d & 15, t = (d >> 4) & 3, h = (d >> 6) & 1, c = d >> 7;
        const int hi = (e >> 3) & 3, j = e & 7, eb = e >> 5;
        char* ibase = wsb + OFF_BFI + (size_t)((c * 2 + h) * 48) * 4096
                    + t * 1024 + hi * 256 + fm * 16 + j * 2;
#pragma unroll
        for (int s = 0; s < 6; ++s)
            *(unsigned short*)(ibase + (size_t)(s * 8 + eb) * 4096) = f2bf(g[s]);

        *(unsigned short*)(wsb + OFF_BFT + (size_t)((c * 2 + h) * 8 + eb) * 4096
                           + t * 1024 + hi * 256 + fm * 16 + j * 2) = f2bf(w1);

        if (e == 0)
            ((float*)(wsb + OFF_BI))[d] = b1[d] + b2[d] + 2.0f * b3[d] + 3.0f * b4[d];
        return;
    }

    // ---- edge correction, block = (d, 8-batch chunk); coalesced weight rows.
    {
        __shared__ float cls[16];
        const int cb = blockIdx.x - CORR_BASE;   // 0..4095
        const int d  = cb >> 3;                  // 0..511
        const int bq = (cb & 7) * 8;             // batch chunk base
        const int e  = tid;                      // 0..255

        if (tid < 16) cls[tid] = 0.f;

        const float w31 = W3[(size_t)d * 768 + 3 * e + 1];
        const float w32 = W3[(size_t)d * 768 + 3 * e + 2];
        const float4 w4v = *(const float4*)(W4 + (size_t)d * 1024 + 4 * e);
        const float w41 = w4v.y, w42 = w4v.z, w43 = w4v.w;

        const float c00 = w31 + w41 + w42;
        const float c01 = w32 + w42 + w43;
        const float c02 = w43;
        __syncthreads();

#pragma unroll
        for (int bi = 0; bi < 8; ++bi) {
            const float* xr = X + (size_t)(bq + bi) * (SDIM * EDIM) + e;
            const float x0 = xr[0], x1 = xr[EDIM], x2 = xr[2 * EDIM];
            float a0 = c00 * x0 + c01 * x1 + c02 * x2;
            float a1 = w41 * x0 + w42 * x1 + w43 * x2;
#pragma unroll
            for (int off = 32; off >= 1; off >>= 1) {
                a0 += __shfl_xor(a0, off, 64);
                a1 += __shfl_xor(a1, off, 64);
            }
            if ((tid & 63) == 0) {
                atomicAdd(&cls[bi * 2 + 0], a0);
                atomicAdd(&cls[bi * 2 + 1], a1);
            }
        }
        __syncthreads();

        if (tid < 16) {
            const int s = tid & 1;
            const float bc = s ? b4[d] : (b3[d] + 2.f * b4[d]);
            ((float*)(wsb + OFF_CORR))[(size_t)d * 128 + bq * 2 + tid] = -cls[tid] - bc;
        }
    }
}

// ============ launch 2: 8-wave depth-2 pipelined GEMM (R8: 2x TLP) ============
// 512 blocks x 512 threads (8 waves). Same 128x128 tile & natural grid
// (A-locality: FETCH 19MB verified R6). Wave w owns a 64x32 sub-tile:
// row-group w>>2 (64 rows), col-quarter w&3 (32 cols) -> acc[4][2],
// 8 MFMA/phase/wave, 2 B-frags/phase/wave, 1 gll stage/phase/wave.
// 16 waves/CU (4/SIMD) vs R7's 8 -> tests the TLP-floor hypothesis after
// 4 null schedule variants at 2 waves/SIMD. Depth-2 prefetch, 4 A-buffers,
// ONE barrier/phase, counted vmcnt(3) (= next tile's 3 ops in flight across
// every barrier; never drained to 0 in-loop).
#define GLL(src, dst) \
    __builtin_amdgcn_global_load_lds((const __attribute__((address_space(1))) void*)(src), \
                                     (__attribute__((address_space(3))) void*)(dst), 16, 0, 0)

__global__ __launch_bounds__(512, 4) void mega(
    const unsigned short* __restrict__ Xp,
    const char* __restrict__ wsb,
    const float* __restrict__ b1,
    float* __restrict__ out)
{
    __shared__ __align__(16) char smem[32768];   // 4 x 8KB A buffers
    const int id  = blockIdx.x;                  // natural: XCD = id%8 = strip%8
    const int strip = id & 127;                  // 128 strips x 128 rows
    const int c     = id >> 7;                   // col block 0..3
    const int col0  = c * 128;
    const int tid = threadIdx.x;
    const int w = tid >> 6, l = tid & 63;

    // A staging: wave w stages rows [16w, 16w+16) of the strip (1 gll x 16 rows x 64B)
    const int sub = l >> 2;                                // row within 16-row group
    const int swz = (((l & 3) ^ ((sub >> 1) & 3)) * 16);   // pre-swizzled source slot
    const int ra  = strip * 128 + 16 * w + sub;
    const int ba  = ra >> 8, sa = ra & 255;

    const int oA = (16 * w) * 64;                // wave-uniform LDS stage offset
    char* q0 = smem;
    char* q1 = smem + 8192;
    char* q2 = smem + 16384;
    char* q3 = smem + 24576;

    const int wrg = (w >> 2) * 64;               // wave row-group offset (0 or 64)
    const int qc  = w & 3;                       // wave col-quarter (32 cols)
    const int fm  = l & 15;
    const int rslot = (((l >> 4) ^ ((fm >> 1) & 3)) * 16);  // read-side XOR (matches source swz)

    // B frag pointers: half h = qc>>1, frag t = (qc&1)*2 + j  (cols qc*32 + j*16)
    const int hq   = qc >> 1;
    const int toff = (qc & 1) * 2048;
    const char* bfi = wsb + OFF_BFI + (size_t)(c * 2 + hq) * (48 * 4096) + toff + l * 16;
    const char* bft = wsb + OFF_BFT + (size_t)(c * 2 + hq) * (8 * 4096)  + toff + l * 16;

    f32x4 acc[4][2];
    const char* ga;

    auto LOADB = [&](bf16x8 (&dst)[2], const char* base, int kt) {
#pragma unroll
        for (int j = 0; j < 2; ++j)
            dst[j] = *(const bf16x8*)(base + (size_t)kt * 4096 + j * 1024);
    };
    auto STAGE = [&](char* buf) {
        GLL(ga, buf + oA);
        ga += 64;
    };
    auto COMP = [&](const char* buf, const bf16x8 (&bfr)[2]) {
        bf16x8 af[4];
#pragma unroll
        for (int t = 0; t < 4; ++t)
            af[t] = *(const bf16x8*)(buf + (wrg + t * 16 + fm) * 64 + rslot);
#pragma unroll
        for (int i = 0; i < 4; ++i)
#pragma unroll
            for (int j = 0; j < 2; ++j)
                acc[i][j] = __builtin_amdgcn_mfma_f32_16x16x32_bf16(af[i], bfr[j], acc[i][j], 0, 0, 0);
    };

#define PHASE_W3  asm volatile("s_waitcnt vmcnt(3) lgkmcnt(0)" ::: "memory"); \
                  __builtin_amdgcn_s_barrier();
#define PHASE_W0  asm volatile("s_waitcnt vmcnt(0) lgkmcnt(0)" ::: "memory"); \
                  __builtin_amdgcn_s_barrier();
#define DO_COMP(Q, B) __builtin_amdgcn_s_setprio(1); COMP(Q, B); __builtin_amdgcn_s_setprio(0);

    auto GEMM = [&](const char* bbase, int nk) {   // nk % 4 == 0, nk >= 8
        bf16x8 b0[2], b1r[2], b2[2], b3[2];
        STAGE(q0); LOADB(b0,  bbase, 0);
        STAGE(q1); LOADB(b1r, bbase, 1);           // 6 ops outstanding
#pragma unroll 1
        for (int kt = 0; kt + 4 < nk; kt += 4) {
            PHASE_W3; STAGE(q2); LOADB(b2,  bbase, kt + 2); DO_COMP(q0, b0);
            PHASE_W3; STAGE(q3); LOADB(b3,  bbase, kt + 3); DO_COMP(q1, b1r);
            PHASE_W3; STAGE(q0); LOADB(b0,  bbase, kt + 4); DO_COMP(q2, b2);
            PHASE_W3; STAGE(q1); LOADB(b1r, bbase, kt + 5); DO_COMP(q3, b3);
        }
        // final 4 phases (kt = nk-4): stage only nk-2, nk-1
        PHASE_W3; STAGE(q2); LOADB(b2, bbase, nk - 2); DO_COMP(q0, b0);
        PHASE_W3; STAGE(q3); LOADB(b3, bbase, nk - 1); DO_COMP(q1, b1r);
        PHASE_W3;                                      DO_COMP(q2, b2);
        PHASE_W0;                                      DO_COMP(q3, b3);
    };

    // epilogue: C/D layout col = lane&15, row = (lane>>4)*4 + reg
    auto EPI = [&](int s_base, bool with_corr) {
        const float* bias = with_corr ? (const float*)(wsb + OFF_BI) : b1;
        const float* corr = (const float*)(wsb + OFF_CORR);   // [d][b*2+s]
        const int ocol = col0 + qc * 32 + fm;
        const int rq   = (l >> 4) * 4;
        float bv[2];
#pragma unroll
        for (int j = 0; j < 2; ++j) bv[j] = bias[ocol + j * 16];
#pragma unroll
        for (int i = 0; i < 4; ++i) {
#pragma unroll
            for (int r = 0; r < 4; ++r) {
                const int rr  = strip * 128 + wrg + i * 16 + rq + r;
                const int ssl = rr & 255;
                const int bb  = rr >> 8;
                float* op = out + ((size_t)(bb * SDIM + s_base + ssl)) * DDIM + ocol;
                if (with_corr && ssl < 2) {
                    const float* cp = corr + (size_t)ocol * 128 + bb * 2 + ssl;
#pragma unroll
                    for (int j = 0; j < 2; ++j)
                        op[j * 16] = acc[i][j][r] + bv[j] + cp[(size_t)j * 16 * 128];
                } else {
#pragma unroll
                    for (int j = 0; j < 2; ++j)
                        op[j * 16] = acc[i][j][r] + bv[j];
                }
            }
        }
    };

    // ---- interior: A row r=(b,s) is Xp[b][s : s+6][:] flattened (im2col) ----
#pragma unroll
    for (int i = 0; i < 4; ++i)
#pragma unroll
        for (int j = 0; j < 2; ++j) acc[i][j] = (f32x4){0.f, 0.f, 0.f, 0.f};
    ga = (const char*)(Xp + (size_t)(ba * SPAD + sa) * EDIM) + swz;
    GEMM(bfi, 48);
    EPI(0, true);

    // ---- tail: s in [256,512), unigram only: A row = Xp[b][s+2][:] = X[b][s][:] ----
#pragma unroll
    for (int i = 0; i < 4; ++i)
#pragma unroll
        for (int j = 0; j < 2; ++j) acc[i][j] = (f32x4){0.f, 0.f, 0.f, 0.f};
    ga = (const char*)(Xp + (size_t)(ba * SPAD + 258 + sa) * EDIM) + swz;
    GEMM(bft, 8);
    EPI(256, false);
}

extern "C" void kernel_launch(void* const* d_in, const int* in_sizes, int n_in,
                              void* d_out, int out_size, void* d_ws, size_t ws_size,
                              hipStream_t stream)
{
    const float* X  = (const float*)d_in[0];
    const float* W1 = (const float*)d_in[1];
    const float* b1 = (const float*)d_in[2];
    const float* W2 = (const float*)d_in[3];
    const float* b2 = (const float*)d_in[4];
    const float* W3 = (const float*)d_in[5];
    const float* b3 = (const float*)d_in[6];
    const float* W4 = (const float*)d_in[7];
    const float* b4 = (const float*)d_in[8];
    float* out = (float*)d_out;
    char*  wsb = (char*)d_ws;

    prep_all<<<dim3(PREP_BLOCKS), dim3(256), 0, stream>>>(X, W1, b1, W2, b2, W3, b3, W4, b4, wsb);

    mega<<<dim3(512), dim3(512), 0, stream>>>(
        (const unsigned short*)(wsb + OFF_XP), wsb, b1, out);
}

// Round 9
// 158.348 us; speedup vs baseline: 1.0705x; 1.0075x over previous
//
#include <hip/hip_runtime.h>
#include <hip/hip_bf16.h>

// B=64, S=512, E=256, D=512
#define EDIM 256
#define SDIM 512
#define BDIM 64
#define DDIM 512
#define SPAD 514   // padded S rows per batch in Xp (2 zero rows at front)

// ws byte offsets
#define OFF_XP    0u           // bf16 [64][514][256]  = 16,842,752 B
#define OFF_BFI   16842752u    // bf16 frag-major interior weights = 1,572,864 B
                               //   addr = ((c*2+h)*48 + kt)*4096 + t*1024 + hi*256 + fm*16 + j*2
                               //   holds G_int[d = c*128+h*64+t*16+fm][k = kt*32 + hi*8 + j]
#define OFF_BFT   18415616u    // bf16 frag-major tail (W1) weights = 262,144 B (same scheme, 8 kt)
#define OFF_CORR  18677760u    // f32  [512][128]  (layout [d][b*2+s])
#define OFF_BI    18939904u    // f32  [512]

// prep grid partition
#define CVT_BLOCKS  4112       // 64*514*32 / 256
#define WB_BASE     4112       // + 512 weight blocks (one per d)
#define CORR_BASE   4624       // + 4096 corr blocks (512 d x 8 b-chunks)
#define PREP_BLOCKS 8720

typedef __attribute__((ext_vector_type(8))) __bf16 bf16x8;
typedef __attribute__((ext_vector_type(4))) float  f32x4;
typedef __attribute__((ext_vector_type(8))) unsigned short ushort8v;

__device__ __forceinline__ unsigned short f2bf(float f) {
    unsigned int u = __float_as_uint(f);
    u = (u + 0x7fffu + ((u >> 16) & 1u)) >> 16;   // RNE
    return (unsigned short)u;
}

// ============ launch 1: cvt_pad + weight-fragment + edge-correction ============
__global__ __launch_bounds__(256) void prep_all(
    const float* __restrict__ X,
    const float* __restrict__ W1, const float* __restrict__ b1,
    const float* __restrict__ W2, const float* __restrict__ b2,
    const float* __restrict__ W3, const float* __restrict__ b3,
    const float* __restrict__ W4, const float* __restrict__ b4,
    char* __restrict__ wsb)
{
    const int tid = threadIdx.x;

    if (blockIdx.x < CVT_BLOCKS) {
        // ---- bf16 copy of X with 2 zero rows prepended per batch, 8 elem/thread ----
        unsigned short* Xp = (unsigned short*)(wsb + OFF_XP);
        const int i   = blockIdx.x * 256 + tid;    // [0, 64*514*32)
        const int row = i >> 5;                    // b*514 + j
        const int q   = i & 31;                    // 8-elem group
        const int b   = row / SPAD;
        const int j   = row - b * SPAD;
        ushort8v v;
        if (j < 2) {
            v = (ushort8v)0;
        } else {
            const float* src = X + ((size_t)(b * SDIM + j - 2)) * EDIM + q * 8;
            const float4 f0 = *(const float4*)(src);
            const float4 f1 = *(const float4*)(src + 4);
            v[0] = f2bf(f0.x); v[1] = f2bf(f0.y); v[2] = f2bf(f0.z); v[3] = f2bf(f0.w);
            v[4] = f2bf(f1.x); v[5] = f2bf(f1.y); v[6] = f2bf(f1.z); v[7] = f2bf(f1.w);
        }
        *(ushort8v*)(Xp + (size_t)row * EDIM + q * 8) = v;
        return;
    }

    if (blockIdx.x < CORR_BASE) {
        // ---- combined weights -> fragment-major, one block per d (coalesced reads) ----
        // G_int[d][k], k = shift*256 + e, shift 0..5 (delta grouping, R0 derivation):
        //   s0: w40 | s1: w30+w40+w41 | s2: w1+w20+w30+w31+w40+w41+w42
        //   s3: w21+w31+w32+w41+w42+w43 | s4: w32+w42+w43 | s5: w43
        const int d = blockIdx.x - WB_BASE;  // 0..511
        const int e = tid;                   // 0..255
        const int de = d * EDIM + e;

        const float w1  = W1[de];
        const float w20 = W2[de * 2 + 0], w21 = W2[de * 2 + 1];
        const float w30 = W3[de * 3 + 0], w31 = W3[de * 3 + 1], w32 = W3[de * 3 + 2];
        const float w40 = W4[de * 4 + 0], w41 = W4[de * 4 + 1], w42 = W4[de * 4 + 2], w43 = W4[de * 4 + 3];

        float g[6];
        g[0] = w40;
        g[1] = w30 + w40 + w41;
        g[2] = w1 + w20 + w30 + w31 + w40 + w41 + w42;
        g[3] = w21 + w31 + w32 + w41 + w42 + w43;
        g[4] = w32 + w42 + w43;
        g[5] = w43;

        const int fm = d & 15, t = (d >> 4) & 3, h = (d >> 6) & 1, c = d >> 7;
        const int hi = (e >> 3) & 3, j = e & 7, eb = e >> 5;
        char* ibase = wsb + OFF_BFI + (size_t)((c * 2 + h) * 48) * 4096
                    + t * 1024 + hi * 256 + fm * 16 + j * 2;
#pragma unroll
        for (int s = 0; s < 6; ++s)
            *(unsigned short*)(ibase + (size_t)(s * 8 + eb) * 4096) = f2bf(g[s]);

        *(unsigned short*)(wsb + OFF_BFT + (size_t)((c * 2 + h) * 8 + eb) * 4096
                           + t * 1024 + hi * 256 + fm * 16 + j * 2) = f2bf(w1);

        if (e == 0)
            ((float*)(wsb + OFF_BI))[d] = b1[d] + b2[d] + 2.0f * b3[d] + 3.0f * b4[d];
        return;
    }

    // ---- edge correction, block = (d, 8-batch chunk); coalesced weight rows.
    {
        __shared__ float cls[16];
        const int cb = blockIdx.x - CORR_BASE;   // 0..4095
        const int d  = cb >> 3;                  // 0..511
        const int bq = (cb & 7) * 8;             // batch chunk base
        const int e  = tid;                      // 0..255

        if (tid < 16) cls[tid] = 0.f;

        const float w31 = W3[(size_t)d * 768 + 3 * e + 1];
        const float w32 = W3[(size_t)d * 768 + 3 * e + 2];
        const float4 w4v = *(const float4*)(W4 + (size_t)d * 1024 + 4 * e);
        const float w41 = w4v.y, w42 = w4v.z, w43 = w4v.w;

        const float c00 = w31 + w41 + w42;
        const float c01 = w32 + w42 + w43;
        const float c02 = w43;
        __syncthreads();

#pragma unroll
        for (int bi = 0; bi < 8; ++bi) {
            const float* xr = X + (size_t)(bq + bi) * (SDIM * EDIM) + e;
            const float x0 = xr[0], x1 = xr[EDIM], x2 = xr[2 * EDIM];
            float a0 = c00 * x0 + c01 * x1 + c02 * x2;
            float a1 = w41 * x0 + w42 * x1 + w43 * x2;
#pragma unroll
            for (int off = 32; off >= 1; off >>= 1) {
                a0 += __shfl_xor(a0, off, 64);
                a1 += __shfl_xor(a1, off, 64);
            }
            if ((tid & 63) == 0) {
                atomicAdd(&cls[bi * 2 + 0], a0);
                atomicAdd(&cls[bi * 2 + 1], a1);
            }
        }
        __syncthreads();

        if (tid < 16) {
            const int s = tid & 1;
            const float bc = s ? b4[d] : (b3[d] + 2.f * b4[d]);
            ((float*)(wsb + OFF_CORR))[(size_t)d * 128 + bq * 2 + tid] = -cls[tid] - bc;
        }
    }
}

// ============ launch 2: K=64-per-phase pipelined GEMM (R9: halve phase count) ============
// Empirical law from R1/R2/R7/R8: per-block phase time pinned at ~820ns
// regardless of sync flavor / depth / waves / per-phase work -> wall time =
// phases x 820ns. R9 halves phases: K=64 per phase -> 24 interior + 4 tail.
// 512 blocks x 512 thr (8 waves), 128x128 tile, natural grid (FETCH 19MB,
// R6-verified). 4 LDS A-buffers x 16KB (128 rows x 128B), depth-2 prefetch,
// ONE barrier/phase, vmcnt(6) = next set's {2 GLL + 4 B-loads} in flight
// across every barrier (never 0 in-loop). New 8-slot swizzle for 128B rows:
// slot ^= row&7 -> per 16-lane phase exactly 2 lanes per 4-bank group (free
// per m136), same property as the verified 4-slot layout. Source-side:
// (l&7)^(l>>3) (row&7 == l>>3 for both 8-row GLL groups); read-side XOR in
// compile-time slot constants.
#define GLL(src, dst) \
    __builtin_amdgcn_global_load_lds((const __attribute__((address_space(1))) void*)(src), \
                                     (__attribute__((address_space(3))) void*)(dst), 16, 0, 0)

__global__ __launch_bounds__(512, 4) void mega(
    const unsigned short* __restrict__ Xp,
    const char* __restrict__ wsb,
    const float* __restrict__ b1,
    float* __restrict__ out)
{
    __shared__ __align__(16) char smem[65536];   // 4 x 16KB A buffers
    const int id  = blockIdx.x;                  // natural: XCD = id%8 = strip%8
    const int strip = id & 127;                  // 128 strips x 128 rows
    const int c     = id >> 7;                   // col block 0..3
    const int col0  = c * 128;
    const int tid = threadIdx.x;
    const int w = tid >> 6, l = tid & 63;

    // A staging: wave w stages rows [16w,16w+16): 2 GLL x 8 rows x 128B
    const int swz = ((l & 7) ^ (l >> 3)) * 16;   // pre-swizzled source slot (8 slots)
    const int r0  = strip * 128 + 16 * w + (l >> 3);
    const int r1  = r0 + 8;
    const int ba0 = r0 >> 8, sa0 = r0 & 255;
    const int ba1 = r1 >> 8, sa1 = r1 & 255;

    const int oA0 = (16 * w) * 128;              // wave-uniform LDS stage offsets
    const int oA1 = oA0 + 1024;
    char* q0 = smem;
    char* q1 = smem + 16384;
    char* q2 = smem + 32768;
    char* q3 = smem + 49152;

    const int wrg = (w >> 2) * 64;               // wave row-group (0 or 64)
    const int qc  = w & 3;                       // wave col-quarter (32 cols)
    const int fm  = l & 15;
    const int hi4 = l >> 4;
    // read slots (bytes) for k-step 0 / 1 within the 64-K phase
    const int rs0 = ((hi4)     ^ (fm & 7)) * 16;
    const int rs1 = ((4 + hi4) ^ (fm & 7)) * 16;

    // B frag pointers: half hq = qc>>1, frag t = (qc&1)*2 + j  (cols qc*32 + j*16)
    const int hq   = qc >> 1;
    const int toff = (qc & 1) * 2048;
    const char* bfi = wsb + OFF_BFI + (size_t)(c * 2 + hq) * (48 * 4096) + toff + l * 16;
    const char* bft = wsb + OFF_BFT + (size_t)(c * 2 + hq) * (8 * 4096)  + toff + l * 16;

    f32x4 acc[4][2];
    const char *ga0, *ga1;

    // one B set per phase: 4 frags = {ks 0,1} x {j 0,1}, k32 = 2*ph + ks
    auto LOADB = [&](bf16x8 (&dst)[4], const char* base, int ph) {
#pragma unroll
        for (int ks = 0; ks < 2; ++ks)
#pragma unroll
            for (int j = 0; j < 2; ++j)
                dst[ks * 2 + j] = *(const bf16x8*)(base + (size_t)(2 * ph + ks) * 4096 + j * 1024);
    };
    auto STAGE = [&](char* buf) {
        GLL(ga0, buf + oA0);
        GLL(ga1, buf + oA1);
        ga0 += 128; ga1 += 128;
    };
    auto COMP = [&](const char* buf, const bf16x8 (&b)[4]) {
#pragma unroll
        for (int ks = 0; ks < 2; ++ks) {
            bf16x8 af[4];
            const int rs = ks ? rs1 : rs0;
#pragma unroll
            for (int t = 0; t < 4; ++t)
                af[t] = *(const bf16x8*)(buf + (wrg + t * 16 + fm) * 128 + rs);
#pragma unroll
            for (int i = 0; i < 4; ++i)
#pragma unroll
                for (int j = 0; j < 2; ++j)
                    acc[i][j] = __builtin_amdgcn_mfma_f32_16x16x32_bf16(af[i], b[ks * 2 + j], acc[i][j], 0, 0, 0);
        }
    };

#define PH6  asm volatile("s_waitcnt vmcnt(6) lgkmcnt(0)" ::: "memory"); \
             __builtin_amdgcn_s_barrier();
#define PH0  asm volatile("s_waitcnt vmcnt(0) lgkmcnt(0)" ::: "memory"); \
             __builtin_amdgcn_s_barrier();
#define DO_COMP(Q, B) __builtin_amdgcn_s_setprio(1); COMP(Q, B); __builtin_amdgcn_s_setprio(0);

    auto GEMM = [&](const char* bbase, int np) {   // np % 4 == 0, np >= 4
        bf16x8 b0[4], b1r[4], b2[4], b3[4];
        STAGE(q0); LOADB(b0,  bbase, 0);
        STAGE(q1); LOADB(b1r, bbase, 1);           // 12 ops outstanding
#pragma unroll 1
        for (int p = 0; p + 4 < np; p += 4) {
            PH6; STAGE(q2); LOADB(b2,  bbase, p + 2); DO_COMP(q0, b0);
            PH6; STAGE(q3); LOADB(b3,  bbase, p + 3); DO_COMP(q1, b1r);
            PH6; STAGE(q0); LOADB(b0,  bbase, p + 4); DO_COMP(q2, b2);
            PH6; STAGE(q1); LOADB(b1r, bbase, p + 5); DO_COMP(q3, b3);
        }
        // final 4 phases: stage only np-2, np-1
        PH6; STAGE(q2); LOADB(b2, bbase, np - 2); DO_COMP(q0, b0);
        PH6; STAGE(q3); LOADB(b3, bbase, np - 1); DO_COMP(q1, b1r);
        PH6;                                      DO_COMP(q2, b2);
        PH0;                                      DO_COMP(q3, b3);
    };

    // epilogue: C/D layout col = lane&15, row = (lane>>4)*4 + reg
    auto EPI = [&](int s_base, bool with_corr) {
        const float* bias = with_corr ? (const float*)(wsb + OFF_BI) : b1;
        const float* corr = (const float*)(wsb + OFF_CORR);   // [d][b*2+s]
        const int ocol = col0 + qc * 32 + fm;
        const int rq   = (l >> 4) * 4;
        float bv[2];
#pragma unroll
        for (int j = 0; j < 2; ++j) bv[j] = bias[ocol + j * 16];
#pragma unroll
        for (int i = 0; i < 4; ++i) {
#pragma unroll
            for (int r = 0; r < 4; ++r) {
                const int rr  = strip * 128 + wrg + i * 16 + rq + r;
                const int ssl = rr & 255;
                const int bb  = rr >> 8;
                float* op = out + ((size_t)(bb * SDIM + s_base + ssl)) * DDIM + ocol;
                if (with_corr && ssl < 2) {
                    const float* cp = corr + (size_t)ocol * 128 + bb * 2 + ssl;
#pragma unroll
                    for (int j = 0; j < 2; ++j)
                        op[j * 16] = acc[i][j][r] + bv[j] + cp[(size_t)j * 16 * 128];
                } else {
#pragma unroll
                    for (int j = 0; j < 2; ++j)
                        op[j * 16] = acc[i][j][r] + bv[j];
                }
            }
        }
    };

    // ---- interior: A row r=(b,s) is Xp[b][s : s+6][:] flattened (im2col), 24 phases ----
#pragma unroll
    for (int i = 0; i < 4; ++i)
#pragma unroll
        for (int j = 0; j < 2; ++j) acc[i][j] = (f32x4){0.f, 0.f, 0.f, 0.f};
    ga0 = (const char*)(Xp + (size_t)(ba0 * SPAD + sa0) * EDIM) + swz;
    ga1 = (const char*)(Xp + (size_t)(ba1 * SPAD + sa1) * EDIM) + swz;
    GEMM(bfi, 24);
    EPI(0, true);

    // ---- tail: s in [256,512), unigram only: A row = Xp[b][s+2][:], 4 phases ----
#pragma unroll
    for (int i = 0; i < 4; ++i)
#pragma unroll
        for (int j = 0; j < 2; ++j) acc[i][j] = (f32x4){0.f, 0.f, 0.f, 0.f};
    ga0 = (const char*)(Xp + (size_t)(ba0 * SPAD + 258 + sa0) * EDIM) + swz;
    ga1 = (const char*)(Xp + (size_t)(ba1 * SPAD + 258 + sa1) * EDIM) + swz;
    GEMM(bft, 4);
    EPI(256, false);
}

extern "C" void kernel_launch(void* const* d_in, const int* in_sizes, int n_in,
                              void* d_out, int out_size, void* d_ws, size_t ws_size,
                              hipStream_t stream)
{
    const float* X  = (const float*)d_in[0];
    const float* W1 = (const float*)d_in[1];
    const float* b1 = (const float*)d_in[2];
    const float* W2 = (const float*)d_in[3];
    const float* b2 = (const float*)d_in[4];
    const float* W3 = (const float*)d_in[5];
    const float* b3 = (const float*)d_in[6];
    const float* W4 = (const float*)d_in[7];
    const float* b4 = (const float*)d_in[8];
    float* out = (float*)d_out;
    char*  wsb = (char*)d_ws;

    prep_all<<<dim3(PREP_BLOCKS), dim3(256), 0, stream>>>(X, W1, b1, W2, b2, W3, b3, W4, b4, wsb);

    mega<<<dim3(512), dim3(512), 0, stream>>>(
        (const unsigned short*)(wsb + OFF_XP), wsb, b1, out);
}